// Round 14
// baseline (217.787 us; speedup 1.0000x reference)
//
#include <hip/hip_runtime.h>

#define N_NODES 50000
#define N_EDGES 800000
#define DIM 96
#define FEAT_ELEMS (N_NODES * DIM)
#define NBLK 196  // ceil(50000/256)
#define NODES_PER_XCD 6250   // 8 * 6250 = 50000
#define FILL_CHUNK 2048      // edges per fill block; 391 chunks cover 800k
#define FILL_GRID (391 * 8)  // 3128 blocks

typedef __attribute__((ext_vector_type(8))) short short8;   // 8 bf16 (4 VGPRs)
typedef __attribute__((ext_vector_type(4))) float float4v;  // 4 fp32 acc

// ---------------------------------------------------------------------------
// bf16 helpers via raw bit ops
// ---------------------------------------------------------------------------
__device__ __forceinline__ float bf16_to_f32(unsigned short u) {
    unsigned int w = ((unsigned int)u) << 16;
    float f;
    __builtin_memcpy(&f, &w, 4);
    return f;
}
__device__ __forceinline__ unsigned short f32_to_bf16_rne(float f) {
    unsigned int w;
    __builtin_memcpy(&w, &f, 4);
    unsigned int r = (w + 0x7FFFu + ((w >> 16) & 1u)) >> 16;
    return (unsigned short)r;
}

__device__ __forceinline__ int edge_at(const void* ep, int is64, int idx) {
    if (is64) return (int)((const long long*)ep)[idx];
    return ((const int*)ep)[idx];
}

// ---------------------------------------------------------------------------
// prolog: blocks [0,NBLK) zero cnt; block NBLK detects edge dtype (int64 =>
// odd 32-bit words all zero => flagE=1); block NBLK+1 detects float dtype of
// x (bf16 => bits14..7 is a N(0,1) bf16 exponent in [100,135] => flagF=1).
// ---------------------------------------------------------------------------
__global__ __launch_bounds__(256) void prolog_kernel(const unsigned int* edges,
                                                     const unsigned int* x,
                                                     int* flagE, int* flagF, int* cnt) {
    __shared__ unsigned int sh[256];
    int t = threadIdx.x;
    int b = blockIdx.x;
    if (b < NBLK) {
        int i = b * 256 + t;
        if (i < N_NODES) cnt[i] = 0;
        return;
    }
    if (b == NBLK) {
        if (t < 64) {
            unsigned int acc = 0;
            for (int k = 0; k < 4; ++k) {
                int idx = t * 4 + k;           // 0..255
                int pos = 1 + 2 * idx * 3109;  // odd words, max 1,585,591 < 1.6M
                acc |= edges[pos];
            }
            sh[t] = acc;
        }
        __syncthreads();
        if (t == 0) {
            unsigned int a = 0;
            for (int i = 0; i < 64; ++i) a |= sh[i];
            *flagE = (a == 0u) ? 1 : 0;
        }
        return;
    }
    // b == NBLK+1: feature dtype
    unsigned int w = x[t * 9000];  // max 2,295,000 < 2.4M words (bf16 interp)
    unsigned int e = (w >> 7) & 0xFFu;
    sh[t] = (e >= 100u && e <= 135u) ? 1u : 0u;
    __syncthreads();
    if (t == 0) {
        int c = 0;
        for (int i = 0; i < 256; ++i) c += (int)sh[i];
        *flagF = (c >= 128) ? 1 : 0;
    }
}

// ---------------------------------------------------------------------------
// count + compact + rank (rank stored as ushort — max in-degree << 65536)
// ---------------------------------------------------------------------------
__global__ __launch_bounds__(256) void count_compact_kernel(const void* edges,
                                                            const int* flagE, int* cnt,
                                                            unsigned short* srcu,
                                                            unsigned short* dstu,
                                                            unsigned short* rank) {
    int e = blockIdx.x * 256 + threadIdx.x;
    if (e >= N_EDGES) return;
    int is64 = *flagE;
    int s = edge_at(edges, is64, e);
    int d = edge_at(edges, is64, N_EDGES + e);
    srcu[e] = (unsigned short)s;
    dstu[e] = (unsigned short)d;
    rank[e] = (unsigned short)atomicAdd(&cnt[d], 1);
}

// ---------------------------------------------------------------------------
// 3-phase parallel scan of cnt -> row_ptr (+ dinv)
// ---------------------------------------------------------------------------
__global__ __launch_bounds__(256) void scan_blocksum_kernel(const int* cnt, int* blockSums) {
    __shared__ int sh[256];
    int i = blockIdx.x * 256 + threadIdx.x;
    sh[threadIdx.x] = (i < N_NODES) ? cnt[i] : 0;
    __syncthreads();
    for (int off = 128; off > 0; off >>= 1) {
        if (threadIdx.x < off) sh[threadIdx.x] += sh[threadIdx.x + off];
        __syncthreads();
    }
    if (threadIdx.x == 0) blockSums[blockIdx.x] = sh[0];
}

__global__ __launch_bounds__(256) void scan_offsets_kernel(const int* blockSums,
                                                           int* blockOffs, int* row_ptr) {
    __shared__ int sh[256];
    int t = threadIdx.x;
    int v = (t < NBLK) ? blockSums[t] : 0;
    sh[t] = v;
    __syncthreads();
    for (int off = 1; off < 256; off <<= 1) {
        int u = (t >= off) ? sh[t - off] : 0;
        __syncthreads();
        sh[t] += u;
        __syncthreads();
    }
    if (t < NBLK) blockOffs[t] = sh[t] - v;  // exclusive
    if (t == 255) row_ptr[N_NODES] = sh[255];
}

__global__ __launch_bounds__(256) void scan_apply_kernel(const int* cnt, const int* blockOffs,
                                                         int* row_ptr, float* dinv) {
    __shared__ int sh[256];
    int t = threadIdx.x;
    int i = blockIdx.x * 256 + t;
    int c = (i < N_NODES) ? cnt[i] : 0;
    sh[t] = c;
    __syncthreads();
    for (int off = 1; off < 256; off <<= 1) {
        int u = (t >= off) ? sh[t - off] : 0;
        __syncthreads();
        sh[t] += u;
        __syncthreads();
    }
    if (i < N_NODES) {
        int excl = sh[t] - c + blockOffs[blockIdx.x];
        row_ptr[i] = excl;
        dinv[i]    = rsqrtf((float)(c + 1));  // +1 self-loop
    }
}

// ---------------------------------------------------------------------------
// fill, XCD-partitioned (rank-based, no atomics): block b => xcd = b&7 owns
// dst range [xcd*6250, (xcd+1)*6250) and processes edge chunk (b>>3). With
// round-robin blockIdx%8 -> XCD placement, each csr segment is written by ONE
// XCD's L2 => lines collect all ~32 stores before a single writeback (round-13
// fill paid 40 MB of HBM writebacks for a 1.6 MB buffer from cross-XCD
// bouncing). Heuristic is perf-only: if placement differs, behavior equals the
// old full scatter. dstu re-read 8x (+11 MB, L2-resident); srcu/rank 1x.
// ---------------------------------------------------------------------------
__global__ __launch_bounds__(256) void fill_xcd_kernel(const unsigned short* __restrict__ dstu,
                                                       const unsigned short* __restrict__ srcu,
                                                       const unsigned short* __restrict__ rank,
                                                       const int* __restrict__ row_ptr,
                                                       unsigned short* __restrict__ csr_src) {
    int xcd = blockIdx.x & 7;
    int chunk = blockIdx.x >> 3;  // 0..390
    int d0 = xcd * NODES_PER_XCD;
    int d1 = d0 + NODES_PER_XCD;
    int e0 = chunk * FILL_CHUNK;
    #pragma unroll
    for (int i = 0; i < FILL_CHUNK / 256; ++i) {  // 8 iterations
        int e = e0 + i * 256 + threadIdx.x;
        if (e >= N_EDGES) break;
        int d = dstu[e];
        if (d >= d0 && d < d1) {
            csr_src[row_ptr[d] + (int)rank[e]] = srcu[e];
        }
    }
}

// ---------------------------------------------------------------------------
// convert features to bf16 (plain copy if already bf16): 4 elems/thread
// ---------------------------------------------------------------------------
__global__ __launch_bounds__(256) void convert_kernel(const void* x, const int* flagF,
                                                      unsigned short* xb) {
    int i4 = (blockIdx.x * 256 + threadIdx.x) * 4;
    if (i4 >= FEAT_ELEMS) return;
    int isbf16 = *flagF;
    ushort4 o;
    if (isbf16) {
        o = *(const ushort4*)((const unsigned short*)x + i4);
    } else {
        float4 v = *(const float4*)((const float*)x + i4);
        o.x = f32_to_bf16_rne(v.x);
        o.y = f32_to_bf16_rne(v.y);
        o.z = f32_to_bf16_rne(v.z);
        o.w = f32_to_bf16_rne(v.w);
    }
    *(ushort4*)(xb + i4) = o;
}

// ---------------------------------------------------------------------------
// Gather-aggregate (bf16 feat, fp32 accum, bf16 output for the MFMA GEMM):
// 16 lanes per node. Per row: ONE ushort4 (dims lane*4..lane*4+3 of 0..63)
// + ONE ushort2 (dims 64+lane*2..65+lane*2) => 2 load issues/row (was 3).
// ---------------------------------------------------------------------------
__global__ __launch_bounds__(256) void gather_kernel(const unsigned short* __restrict__ feat,
                                                     const int* __restrict__ row_ptr,
                                                     const unsigned short* __restrict__ csr_src,
                                                     const float* __restrict__ dinv,
                                                     unsigned short* __restrict__ aggb) {
    int gid = blockIdx.x * 256 + threadIdx.x;
    int g = gid >> 4;
    int lane = gid & 15;
    if (g >= N_NODES) return;
    float di = dinv[g];
    int o4 = lane * 4;        // offset of the ushort4 part
    int o2 = 64 + lane * 2;   // offset of the ushort2 part
    int gbase = g * DIM;
    ushort4 sv = *(const ushort4*)&feat[gbase + o4];
    ushort2 sw = *(const ushort2*)&feat[gbase + o2];
    float wself = di * di;
    float a0 = wself * bf16_to_f32(sv.x), a1 = wself * bf16_to_f32(sv.y);
    float a2 = wself * bf16_to_f32(sv.z), a3 = wself * bf16_to_f32(sv.w);
    float a4 = wself * bf16_to_f32(sw.x), a5 = wself * bf16_to_f32(sw.y);
    int e = row_ptr[g], e1 = row_ptr[g + 1];
    for (; e + 2 <= e1; e += 2) {
        int s0 = csr_src[e];
        int s1 = csr_src[e + 1];
        float w0 = dinv[s0] * di;
        float w1 = dinv[s1] * di;
        int b0 = s0 * DIM;
        int b1 = s1 * DIM;
        ushort4 p = *(const ushort4*)&feat[b0 + o4];
        ushort2 pw = *(const ushort2*)&feat[b0 + o2];
        ushort4 q = *(const ushort4*)&feat[b1 + o4];
        ushort2 qw = *(const ushort2*)&feat[b1 + o2];
        a0 = fmaf(w0, bf16_to_f32(p.x), a0);  a1 = fmaf(w0, bf16_to_f32(p.y), a1);
        a2 = fmaf(w0, bf16_to_f32(p.z), a2);  a3 = fmaf(w0, bf16_to_f32(p.w), a3);
        a4 = fmaf(w0, bf16_to_f32(pw.x), a4); a5 = fmaf(w0, bf16_to_f32(pw.y), a5);
        a0 = fmaf(w1, bf16_to_f32(q.x), a0);  a1 = fmaf(w1, bf16_to_f32(q.y), a1);
        a2 = fmaf(w1, bf16_to_f32(q.z), a2);  a3 = fmaf(w1, bf16_to_f32(q.w), a3);
        a4 = fmaf(w1, bf16_to_f32(qw.x), a4); a5 = fmaf(w1, bf16_to_f32(qw.y), a5);
    }
    if (e < e1) {
        int s = csr_src[e];
        float w = dinv[s] * di;
        int b0 = s * DIM;
        ushort4 p = *(const ushort4*)&feat[b0 + o4];
        ushort2 pw = *(const ushort2*)&feat[b0 + o2];
        a0 = fmaf(w, bf16_to_f32(p.x), a0);  a1 = fmaf(w, bf16_to_f32(p.y), a1);
        a2 = fmaf(w, bf16_to_f32(p.z), a2);  a3 = fmaf(w, bf16_to_f32(p.w), a3);
        a4 = fmaf(w, bf16_to_f32(pw.x), a4); a5 = fmaf(w, bf16_to_f32(pw.y), a5);
    }
    uint2 ov;
    ov.x = (unsigned int)f32_to_bf16_rne(a0) | ((unsigned int)f32_to_bf16_rne(a1) << 16);
    ov.y = (unsigned int)f32_to_bf16_rne(a2) | ((unsigned int)f32_to_bf16_rne(a3) << 16);
    unsigned int ow = (unsigned int)f32_to_bf16_rne(a4) | ((unsigned int)f32_to_bf16_rne(a5) << 16);
    *(uint2*)&aggb[gbase + o4] = ov;
    *(unsigned int*)&aggb[gbase + o2] = ow;
}

// ---------------------------------------------------------------------------
// MFMA GEMM + bias + ReLU: out[M,96] = relu(A[M,96](bf16) @ W[96,96] + b).
// mfma_f32_16x16x32_bf16, K = 3x32. 256 thr = 4 waves x 16 rows = 64 rows/blk.
// Verified layouts (learn_hip m89/m91/m120): A[m=lane&15][k=(lane>>4)*8+j];
// B[k=(lane>>4)*8+j][n=lane&15]; C/D col=lane&15, row=(lane>>4)*4+reg.
// W pre-swizzled in LDS to B-frag order so K-loop is ds_read_b128 + MFMA.
// outMode: 0=fp32, 1=bf16, 2=follow flagF
// ---------------------------------------------------------------------------
__global__ __launch_bounds__(256) void gemm_mfma_kernel(const unsigned short* __restrict__ A,
                                                        const void* W, const void* bias,
                                                        const int* flagF,
                                                        void* out, int outMode) {
    __shared__ unsigned short Wlin[DIM * DIM];      // 18432 B
    __shared__ unsigned short Wsw[3 * 6 * 64 * 8];  // 18432 B, B-frag order
    __shared__ float bs[DIM];
    int wBf16 = *flagF;
    int outBf16 = (outMode == 2) ? wBf16 : outMode;

    // stage W to LDS as bf16
    if (wBf16) {
        const ushort4* W4 = (const ushort4*)W;
        ushort4* L4 = (ushort4*)Wlin;
        for (int i = threadIdx.x; i < DIM * DIM / 4; i += 256) L4[i] = W4[i];
        if (threadIdx.x < DIM)
            bs[threadIdx.x] = bf16_to_f32(((const unsigned short*)bias)[threadIdx.x]);
    } else {
        const float* Wf = (const float*)W;
        for (int i = threadIdx.x; i < DIM * DIM; i += 256) Wlin[i] = f32_to_bf16_rne(Wf[i]);
        if (threadIdx.x < DIM) bs[threadIdx.x] = ((const float*)bias)[threadIdx.x];
    }
    __syncthreads();

    // build B-fragment-swizzled copy: frag f=(kt*6+nt)*64+lane holds
    // W[kt*32+(lane>>4)*8+j][nt*16+(lane&15)], j=0..7
    for (int f = threadIdx.x; f < 1152; f += 256) {
        int kt = f / 384;
        int rem = f - kt * 384;
        int nt = rem >> 6;
        int ln64 = rem & 63;
        int q = ln64 >> 4, ln = ln64 & 15;
        int k0 = kt * 32 + q * 8;
        int n = nt * 16 + ln;
        unsigned int w0 = (unsigned int)Wlin[(k0 + 0) * DIM + n] |
                          ((unsigned int)Wlin[(k0 + 1) * DIM + n] << 16);
        unsigned int w1 = (unsigned int)Wlin[(k0 + 2) * DIM + n] |
                          ((unsigned int)Wlin[(k0 + 3) * DIM + n] << 16);
        unsigned int w2 = (unsigned int)Wlin[(k0 + 4) * DIM + n] |
                          ((unsigned int)Wlin[(k0 + 5) * DIM + n] << 16);
        unsigned int w3 = (unsigned int)Wlin[(k0 + 6) * DIM + n] |
                          ((unsigned int)Wlin[(k0 + 7) * DIM + n] << 16);
        uint4 pk = make_uint4(w0, w1, w2, w3);
        *(uint4*)&Wsw[f * 8] = pk;
    }
    __syncthreads();

    int wave = threadIdx.x >> 6;
    int lane = threadIdx.x & 63;
    int quad = lane >> 4, ln = lane & 15;
    int m0 = blockIdx.x * 64 + wave * 16;  // wave's 16-row tile
    int arow = m0 + ln;                    // A row this lane supplies
    bool arowok = (arow < N_NODES);

    float4v acc[6];
    #pragma unroll
    for (int nt = 0; nt < 6; ++nt) acc[nt] = (float4v){0.f, 0.f, 0.f, 0.f};

    #pragma unroll
    for (int kt = 0; kt < 3; ++kt) {
        short8 af;
        if (arowok) {
            af = *(const short8*)&A[arow * DIM + kt * 32 + quad * 8];
        } else {
            af = (short8){0, 0, 0, 0, 0, 0, 0, 0};
        }
        #pragma unroll
        for (int nt = 0; nt < 6; ++nt) {
            short8 bf = *(const short8*)&Wsw[((kt * 6 + nt) * 64 + lane) * 8];
            acc[nt] = __builtin_amdgcn_mfma_f32_16x16x32_bf16(af, bf, acc[nt], 0, 0, 0);
        }
    }

    // epilogue: C/D col = ln, row = quad*4 + reg
    #pragma unroll
    for (int nt = 0; nt < 6; ++nt) {
        int n = nt * 16 + ln;
        float bv = bs[n];
        #pragma unroll
        for (int reg = 0; reg < 4; ++reg) {
            int row = m0 + quad * 4 + reg;
            if (row >= N_NODES) continue;
            float v = fmaxf(acc[nt][reg] + bv, 0.0f);
            if (outBf16) ((unsigned short*)out)[row * DIM + n] = f32_to_bf16_rne(v);
            else         ((float*)out)[row * DIM + n] = v;
        }
    }
}

// ---------------------------------------------------------------------------
extern "C" void kernel_launch(void* const* d_in, const int* in_sizes, int n_in,
                              void* d_out, int out_size, void* d_ws, size_t ws_size,
                              hipStream_t stream) {
    const void* x  = d_in[0];
    const void* ei = d_in[1];
    const void* W1 = d_in[2];
    const void* b1 = d_in[3];
    const void* W2 = d_in[4];
    const void* b2 = d_in[5];

    char* base = (char*)d_ws;
    size_t off = 0;
    auto carve = [&](size_t bytes) -> void* {
        void* p = base + off;
        off += (bytes + 255) & ~(size_t)255;
        return p;
    };
    int*            flagE     = (int*)carve(4);
    int*            flagF     = (int*)carve(4);
    int*            cnt       = (int*)carve((size_t)N_NODES * 4);
    int*            row_ptr   = (int*)carve((size_t)(N_NODES + 1) * 4);
    float*          dinv      = (float*)carve((size_t)N_NODES * 4);
    int*            blockSums = (int*)carve((size_t)NBLK * 4);
    int*            blockOffs = (int*)carve((size_t)NBLK * 4);
    unsigned short* srcu      = (unsigned short*)carve((size_t)N_EDGES * 2);
    unsigned short* dstu      = (unsigned short*)carve((size_t)N_EDGES * 2);
    unsigned short* rank      = (unsigned short*)carve((size_t)N_EDGES * 2);
    unsigned short* csr_src   = (unsigned short*)carve((size_t)N_EDGES * 2);
    unsigned short* aggb      = (unsigned short*)carve((size_t)FEAT_ELEMS * 2);
    unsigned short* xb        = (unsigned short*)carve((size_t)FEAT_ELEMS * 2);
    unsigned short* h         = (unsigned short*)carve((size_t)FEAT_ELEMS * 2);

    const int egrid = (N_EDGES + 255) / 256;           // 3125
    const int cgrid = (FEAT_ELEMS / 4 + 255) / 256;    // 4688
    const int agrid = (N_NODES * 16 + 255) / 256;      // 3125
    const int ggrid = (N_NODES + 63) / 64;             // 782

    prolog_kernel<<<NBLK + 2, 256, 0, stream>>>((const unsigned int*)ei,
                                                (const unsigned int*)x, flagE, flagF, cnt);
    count_compact_kernel<<<egrid, 256, 0, stream>>>(ei, flagE, cnt, srcu, dstu, rank);
    scan_blocksum_kernel<<<NBLK, 256, 0, stream>>>(cnt, blockSums);
    scan_offsets_kernel<<<1, 256, 0, stream>>>(blockSums, blockOffs, row_ptr);
    scan_apply_kernel<<<NBLK, 256, 0, stream>>>(cnt, blockOffs, row_ptr, dinv);
    fill_xcd_kernel<<<FILL_GRID, 256, 0, stream>>>(dstu, srcu, rank, row_ptr, csr_src);
    convert_kernel<<<cgrid, 256, 0, stream>>>(x, flagF, xb);

    // ---- layer 1: aggb = A_hat * x ; h = relu(aggb @ W1 + b1) (bf16) ----
    gather_kernel<<<agrid, 256, 0, stream>>>(xb, row_ptr, csr_src, dinv, aggb);
    gemm_mfma_kernel<<<ggrid, 256, 0, stream>>>(aggb, W1, b1, flagF, h, 1);

    // ---- layer 2: aggb = A_hat * h ; out = relu(aggb @ W2 + b2) ----
    gather_kernel<<<agrid, 256, 0, stream>>>(h, row_ptr, csr_src, dinv, aggb);
    gemm_mfma_kernel<<<ggrid, 256, 0, stream>>>(aggb, W2, b2, flagF, d_out, 2);
}

// Round 15
// 214.557 us; speedup vs baseline: 1.0151x; 1.0151x over previous
//
#include <hip/hip_runtime.h>

#define N_NODES 50000
#define N_EDGES 800000
#define DIM 96
#define FEAT_ELEMS (N_NODES * DIM)
#define NBLK 196  // ceil(50000/256)

typedef __attribute__((ext_vector_type(8))) short short8;   // 8 bf16 (4 VGPRs)
typedef __attribute__((ext_vector_type(4))) float float4v;  // 4 fp32 acc

// ---------------------------------------------------------------------------
// bf16 helpers via raw bit ops
// ---------------------------------------------------------------------------
__device__ __forceinline__ float bf16_to_f32(unsigned short u) {
    unsigned int w = ((unsigned int)u) << 16;
    float f;
    __builtin_memcpy(&f, &w, 4);
    return f;
}
__device__ __forceinline__ unsigned short f32_to_bf16_rne(float f) {
    unsigned int w;
    __builtin_memcpy(&w, &f, 4);
    unsigned int r = (w + 0x7FFFu + ((w >> 16) & 1u)) >> 16;
    return (unsigned short)r;
}

__device__ __forceinline__ int edge_at(const void* ep, int is64, int idx) {
    if (is64) return (int)((const long long*)ep)[idx];
    return ((const int*)ep)[idx];
}

// ---------------------------------------------------------------------------
// prolog: blocks [0,NBLK) zero cnt; block NBLK detects edge dtype (int64 =>
// odd 32-bit words all zero => flagE=1); block NBLK+1 detects float dtype of
// x (bf16 => bits14..7 is a N(0,1) bf16 exponent in [100,135] => flagF=1).
// ---------------------------------------------------------------------------
__global__ __launch_bounds__(256) void prolog_kernel(const unsigned int* edges,
                                                     const unsigned int* x,
                                                     int* flagE, int* flagF, int* cnt) {
    __shared__ unsigned int sh[256];
    int t = threadIdx.x;
    int b = blockIdx.x;
    if (b < NBLK) {
        int i = b * 256 + t;
        if (i < N_NODES) cnt[i] = 0;
        return;
    }
    if (b == NBLK) {
        if (t < 64) {
            unsigned int acc = 0;
            for (int k = 0; k < 4; ++k) {
                int idx = t * 4 + k;           // 0..255
                int pos = 1 + 2 * idx * 3109;  // odd words, max 1,585,591 < 1.6M
                acc |= edges[pos];
            }
            sh[t] = acc;
        }
        __syncthreads();
        if (t == 0) {
            unsigned int a = 0;
            for (int i = 0; i < 64; ++i) a |= sh[i];
            *flagE = (a == 0u) ? 1 : 0;
        }
        return;
    }
    // b == NBLK+1: feature dtype
    unsigned int w = x[t * 9000];  // max 2,295,000 < 2.4M words (bf16 interp)
    unsigned int e = (w >> 7) & 0xFFu;
    sh[t] = (e >= 100u && e <= 135u) ? 1u : 0u;
    __syncthreads();
    if (t == 0) {
        int c = 0;
        for (int i = 0; i < 256; ++i) c += (int)sh[i];
        *flagF = (c >= 128) ? 1 : 0;
    }
}

// ---------------------------------------------------------------------------
// count + compact + rank (rank stored as ushort — max in-degree << 65536)
// ---------------------------------------------------------------------------
__global__ __launch_bounds__(256) void count_compact_kernel(const void* edges,
                                                            const int* flagE, int* cnt,
                                                            unsigned short* srcu,
                                                            unsigned short* dstu,
                                                            unsigned short* rank) {
    int e = blockIdx.x * 256 + threadIdx.x;
    if (e >= N_EDGES) return;
    int is64 = *flagE;
    int s = edge_at(edges, is64, e);
    int d = edge_at(edges, is64, N_EDGES + e);
    srcu[e] = (unsigned short)s;
    dstu[e] = (unsigned short)d;
    rank[e] = (unsigned short)atomicAdd(&cnt[d], 1);
}

// ---------------------------------------------------------------------------
// 3-phase parallel scan of cnt -> row_ptr (+ dinv)
// ---------------------------------------------------------------------------
__global__ __launch_bounds__(256) void scan_blocksum_kernel(const int* cnt, int* blockSums) {
    __shared__ int sh[256];
    int i = blockIdx.x * 256 + threadIdx.x;
    sh[threadIdx.x] = (i < N_NODES) ? cnt[i] : 0;
    __syncthreads();
    for (int off = 128; off > 0; off >>= 1) {
        if (threadIdx.x < off) sh[threadIdx.x] += sh[threadIdx.x + off];
        __syncthreads();
    }
    if (threadIdx.x == 0) blockSums[blockIdx.x] = sh[0];
}

__global__ __launch_bounds__(256) void scan_offsets_kernel(const int* blockSums,
                                                           int* blockOffs, int* row_ptr) {
    __shared__ int sh[256];
    int t = threadIdx.x;
    int v = (t < NBLK) ? blockSums[t] : 0;
    sh[t] = v;
    __syncthreads();
    for (int off = 1; off < 256; off <<= 1) {
        int u = (t >= off) ? sh[t - off] : 0;
        __syncthreads();
        sh[t] += u;
        __syncthreads();
    }
    if (t < NBLK) blockOffs[t] = sh[t] - v;  // exclusive
    if (t == 255) row_ptr[N_NODES] = sh[255];
}

__global__ __launch_bounds__(256) void scan_apply_kernel(const int* cnt, const int* blockOffs,
                                                         int* row_ptr, float* dinv) {
    __shared__ int sh[256];
    int t = threadIdx.x;
    int i = blockIdx.x * 256 + t;
    int c = (i < N_NODES) ? cnt[i] : 0;
    sh[t] = c;
    __syncthreads();
    for (int off = 1; off < 256; off <<= 1) {
        int u = (t >= off) ? sh[t - off] : 0;
        __syncthreads();
        sh[t] += u;
        __syncthreads();
    }
    if (i < N_NODES) {
        int excl = sh[t] - c + blockOffs[blockIdx.x];
        row_ptr[i] = excl;
        dinv[i]    = rsqrtf((float)(c + 1));  // +1 self-loop
    }
}

// ---------------------------------------------------------------------------
// fill (rank-based direct scatter, NO atomics): position fully determined by
// row_ptr[dst] + rank. Full-chip parallel. The ~40 MB of scattered-2B-store
// line writebacks is the established floor on this chip (two XCD-locality
// schemes, r9/r10/r14, failed to beat it — blockIdx%8 placement heuristic
// does not pay off on this scheduler).
// ---------------------------------------------------------------------------
__global__ __launch_bounds__(256) void fill_direct_kernel(const unsigned short* __restrict__ dstu,
                                                          const unsigned short* __restrict__ srcu,
                                                          const unsigned short* __restrict__ rank,
                                                          const int* __restrict__ row_ptr,
                                                          unsigned short* __restrict__ csr_src) {
    int e = blockIdx.x * 256 + threadIdx.x;
    if (e >= N_EDGES) return;
    int d = dstu[e];
    int pos = row_ptr[d] + (int)rank[e];
    csr_src[pos] = srcu[e];
}

// ---------------------------------------------------------------------------
// convert features to bf16 (plain copy if already bf16): 4 elems/thread
// ---------------------------------------------------------------------------
__global__ __launch_bounds__(256) void convert_kernel(const void* x, const int* flagF,
                                                      unsigned short* xb) {
    int i4 = (blockIdx.x * 256 + threadIdx.x) * 4;
    if (i4 >= FEAT_ELEMS) return;
    int isbf16 = *flagF;
    ushort4 o;
    if (isbf16) {
        o = *(const ushort4*)((const unsigned short*)x + i4);
    } else {
        float4 v = *(const float4*)((const float*)x + i4);
        o.x = f32_to_bf16_rne(v.x);
        o.y = f32_to_bf16_rne(v.y);
        o.z = f32_to_bf16_rne(v.z);
        o.w = f32_to_bf16_rne(v.w);
    }
    *(ushort4*)(xb + i4) = o;
}

// ---------------------------------------------------------------------------
// Gather-aggregate (bf16 feat, fp32 accum, bf16 output for the MFMA GEMM):
// 16 lanes per node. Per row: ONE ushort4 (dims lane*4..lane*4+3 of 0..63)
// + ONE ushort2 (dims 64+lane*2..65+lane*2) => 2 load issues/row.
// ---------------------------------------------------------------------------
__global__ __launch_bounds__(256) void gather_kernel(const unsigned short* __restrict__ feat,
                                                     const int* __restrict__ row_ptr,
                                                     const unsigned short* __restrict__ csr_src,
                                                     const float* __restrict__ dinv,
                                                     unsigned short* __restrict__ aggb) {
    int gid = blockIdx.x * 256 + threadIdx.x;
    int g = gid >> 4;
    int lane = gid & 15;
    if (g >= N_NODES) return;
    float di = dinv[g];
    int o4 = lane * 4;        // offset of the ushort4 part
    int o2 = 64 + lane * 2;   // offset of the ushort2 part
    int gbase = g * DIM;
    ushort4 sv = *(const ushort4*)&feat[gbase + o4];
    ushort2 sw = *(const ushort2*)&feat[gbase + o2];
    float wself = di * di;
    float a0 = wself * bf16_to_f32(sv.x), a1 = wself * bf16_to_f32(sv.y);
    float a2 = wself * bf16_to_f32(sv.z), a3 = wself * bf16_to_f32(sv.w);
    float a4 = wself * bf16_to_f32(sw.x), a5 = wself * bf16_to_f32(sw.y);
    int e = row_ptr[g], e1 = row_ptr[g + 1];
    for (; e + 2 <= e1; e += 2) {
        int s0 = csr_src[e];
        int s1 = csr_src[e + 1];
        float w0 = dinv[s0] * di;
        float w1 = dinv[s1] * di;
        int b0 = s0 * DIM;
        int b1 = s1 * DIM;
        ushort4 p = *(const ushort4*)&feat[b0 + o4];
        ushort2 pw = *(const ushort2*)&feat[b0 + o2];
        ushort4 q = *(const ushort4*)&feat[b1 + o4];
        ushort2 qw = *(const ushort2*)&feat[b1 + o2];
        a0 = fmaf(w0, bf16_to_f32(p.x), a0);  a1 = fmaf(w0, bf16_to_f32(p.y), a1);
        a2 = fmaf(w0, bf16_to_f32(p.z), a2);  a3 = fmaf(w0, bf16_to_f32(p.w), a3);
        a4 = fmaf(w0, bf16_to_f32(pw.x), a4); a5 = fmaf(w0, bf16_to_f32(pw.y), a5);
        a0 = fmaf(w1, bf16_to_f32(q.x), a0);  a1 = fmaf(w1, bf16_to_f32(q.y), a1);
        a2 = fmaf(w1, bf16_to_f32(q.z), a2);  a3 = fmaf(w1, bf16_to_f32(q.w), a3);
        a4 = fmaf(w1, bf16_to_f32(qw.x), a4); a5 = fmaf(w1, bf16_to_f32(qw.y), a5);
    }
    if (e < e1) {
        int s = csr_src[e];
        float w = dinv[s] * di;
        int b0 = s * DIM;
        ushort4 p = *(const ushort4*)&feat[b0 + o4];
        ushort2 pw = *(const ushort2*)&feat[b0 + o2];
        a0 = fmaf(w, bf16_to_f32(p.x), a0);  a1 = fmaf(w, bf16_to_f32(p.y), a1);
        a2 = fmaf(w, bf16_to_f32(p.z), a2);  a3 = fmaf(w, bf16_to_f32(p.w), a3);
        a4 = fmaf(w, bf16_to_f32(pw.x), a4); a5 = fmaf(w, bf16_to_f32(pw.y), a5);
    }
    uint2 ov;
    ov.x = (unsigned int)f32_to_bf16_rne(a0) | ((unsigned int)f32_to_bf16_rne(a1) << 16);
    ov.y = (unsigned int)f32_to_bf16_rne(a2) | ((unsigned int)f32_to_bf16_rne(a3) << 16);
    unsigned int ow = (unsigned int)f32_to_bf16_rne(a4) | ((unsigned int)f32_to_bf16_rne(a5) << 16);
    *(uint2*)&aggb[gbase + o4] = ov;
    *(unsigned int*)&aggb[gbase + o2] = ow;
}

// ---------------------------------------------------------------------------
// MFMA GEMM + bias + ReLU: out[M,96] = relu(A[M,96](bf16) @ W[96,96] + b).
// mfma_f32_16x16x32_bf16, K = 3x32. 256 thr = 4 waves x 16 rows = 64 rows/blk.
// Verified layouts (learn_hip m89/m91/m120): A[m=lane&15][k=(lane>>4)*8+j];
// B[k=(lane>>4)*8+j][n=lane&15]; C/D col=lane&15, row=(lane>>4)*4+reg.
// W pre-swizzled in LDS to B-frag order so K-loop is ds_read_b128 + MFMA.
// outMode: 0=fp32, 1=bf16, 2=follow flagF
// ---------------------------------------------------------------------------
__global__ __launch_bounds__(256) void gemm_mfma_kernel(const unsigned short* __restrict__ A,
                                                        const void* W, const void* bias,
                                                        const int* flagF,
                                                        void* out, int outMode) {
    __shared__ unsigned short Wlin[DIM * DIM];      // 18432 B
    __shared__ unsigned short Wsw[3 * 6 * 64 * 8];  // 18432 B, B-frag order
    __shared__ float bs[DIM];
    int wBf16 = *flagF;
    int outBf16 = (outMode == 2) ? wBf16 : outMode;

    // stage W to LDS as bf16
    if (wBf16) {
        const ushort4* W4 = (const ushort4*)W;
        ushort4* L4 = (ushort4*)Wlin;
        for (int i = threadIdx.x; i < DIM * DIM / 4; i += 256) L4[i] = W4[i];
        if (threadIdx.x < DIM)
            bs[threadIdx.x] = bf16_to_f32(((const unsigned short*)bias)[threadIdx.x]);
    } else {
        const float* Wf = (const float*)W;
        for (int i = threadIdx.x; i < DIM * DIM; i += 256) Wlin[i] = f32_to_bf16_rne(Wf[i]);
        if (threadIdx.x < DIM) bs[threadIdx.x] = ((const float*)bias)[threadIdx.x];
    }
    __syncthreads();

    // build B-fragment-swizzled copy: frag f=(kt*6+nt)*64+lane holds
    // W[kt*32+(lane>>4)*8+j][nt*16+(lane&15)], j=0..7
    for (int f = threadIdx.x; f < 1152; f += 256) {
        int kt = f / 384;
        int rem = f - kt * 384;
        int nt = rem >> 6;
        int ln64 = rem & 63;
        int q = ln64 >> 4, ln = ln64 & 15;
        int k0 = kt * 32 + q * 8;
        int n = nt * 16 + ln;
        unsigned int w0 = (unsigned int)Wlin[(k0 + 0) * DIM + n] |
                          ((unsigned int)Wlin[(k0 + 1) * DIM + n] << 16);
        unsigned int w1 = (unsigned int)Wlin[(k0 + 2) * DIM + n] |
                          ((unsigned int)Wlin[(k0 + 3) * DIM + n] << 16);
        unsigned int w2 = (unsigned int)Wlin[(k0 + 4) * DIM + n] |
                          ((unsigned int)Wlin[(k0 + 5) * DIM + n] << 16);
        unsigned int w3 = (unsigned int)Wlin[(k0 + 6) * DIM + n] |
                          ((unsigned int)Wlin[(k0 + 7) * DIM + n] << 16);
        uint4 pk = make_uint4(w0, w1, w2, w3);
        *(uint4*)&Wsw[f * 8] = pk;
    }
    __syncthreads();

    int wave = threadIdx.x >> 6;
    int lane = threadIdx.x & 63;
    int quad = lane >> 4, ln = lane & 15;
    int m0 = blockIdx.x * 64 + wave * 16;  // wave's 16-row tile
    int arow = m0 + ln;                    // A row this lane supplies
    bool arowok = (arow < N_NODES);

    float4v acc[6];
    #pragma unroll
    for (int nt = 0; nt < 6; ++nt) acc[nt] = (float4v){0.f, 0.f, 0.f, 0.f};

    #pragma unroll
    for (int kt = 0; kt < 3; ++kt) {
        short8 af;
        if (arowok) {
            af = *(const short8*)&A[arow * DIM + kt * 32 + quad * 8];
        } else {
            af = (short8){0, 0, 0, 0, 0, 0, 0, 0};
        }
        #pragma unroll
        for (int nt = 0; nt < 6; ++nt) {
            short8 bf = *(const short8*)&Wsw[((kt * 6 + nt) * 64 + lane) * 8];
            acc[nt] = __builtin_amdgcn_mfma_f32_16x16x32_bf16(af, bf, acc[nt], 0, 0, 0);
        }
    }

    // epilogue: C/D col = ln, row = quad*4 + reg
    #pragma unroll
    for (int nt = 0; nt < 6; ++nt) {
        int n = nt * 16 + ln;
        float bv = bs[n];
        #pragma unroll
        for (int reg = 0; reg < 4; ++reg) {
            int row = m0 + quad * 4 + reg;
            if (row >= N_NODES) continue;
            float v = fmaxf(acc[nt][reg] + bv, 0.0f);
            if (outBf16) ((unsigned short*)out)[row * DIM + n] = f32_to_bf16_rne(v);
            else         ((float*)out)[row * DIM + n] = v;
        }
    }
}

// ---------------------------------------------------------------------------
extern "C" void kernel_launch(void* const* d_in, const int* in_sizes, int n_in,
                              void* d_out, int out_size, void* d_ws, size_t ws_size,
                              hipStream_t stream) {
    const void* x  = d_in[0];
    const void* ei = d_in[1];
    const void* W1 = d_in[2];
    const void* b1 = d_in[3];
    const void* W2 = d_in[4];
    const void* b2 = d_in[5];

    char* base = (char*)d_ws;
    size_t off = 0;
    auto carve = [&](size_t bytes) -> void* {
        void* p = base + off;
        off += (bytes + 255) & ~(size_t)255;
        return p;
    };
    int*            flagE     = (int*)carve(4);
    int*            flagF     = (int*)carve(4);
    int*            cnt       = (int*)carve((size_t)N_NODES * 4);
    int*            row_ptr   = (int*)carve((size_t)(N_NODES + 1) * 4);
    float*          dinv      = (float*)carve((size_t)N_NODES * 4);
    int*            blockSums = (int*)carve((size_t)NBLK * 4);
    int*            blockOffs = (int*)carve((size_t)NBLK * 4);
    unsigned short* srcu      = (unsigned short*)carve((size_t)N_EDGES * 2);
    unsigned short* dstu      = (unsigned short*)carve((size_t)N_EDGES * 2);
    unsigned short* rank      = (unsigned short*)carve((size_t)N_EDGES * 2);
    unsigned short* csr_src   = (unsigned short*)carve((size_t)N_EDGES * 2);
    unsigned short* aggb      = (unsigned short*)carve((size_t)FEAT_ELEMS * 2);
    unsigned short* xb        = (unsigned short*)carve((size_t)FEAT_ELEMS * 2);
    unsigned short* h         = (unsigned short*)carve((size_t)FEAT_ELEMS * 2);

    const int egrid = (N_EDGES + 255) / 256;           // 3125
    const int cgrid = (FEAT_ELEMS / 4 + 255) / 256;    // 4688
    const int agrid = (N_NODES * 16 + 255) / 256;      // 3125
    const int ggrid = (N_NODES + 63) / 64;             // 782

    prolog_kernel<<<NBLK + 2, 256, 0, stream>>>((const unsigned int*)ei,
                                                (const unsigned int*)x, flagE, flagF, cnt);
    count_compact_kernel<<<egrid, 256, 0, stream>>>(ei, flagE, cnt, srcu, dstu, rank);
    scan_blocksum_kernel<<<NBLK, 256, 0, stream>>>(cnt, blockSums);
    scan_offsets_kernel<<<1, 256, 0, stream>>>(blockSums, blockOffs, row_ptr);
    scan_apply_kernel<<<NBLK, 256, 0, stream>>>(cnt, blockOffs, row_ptr, dinv);
    fill_direct_kernel<<<egrid, 256, 0, stream>>>(dstu, srcu, rank, row_ptr, csr_src);
    convert_kernel<<<cgrid, 256, 0, stream>>>(x, flagF, xb);

    // ---- layer 1: aggb = A_hat * x ; h = relu(aggb @ W1 + b1) (bf16) ----
    gather_kernel<<<agrid, 256, 0, stream>>>(xb, row_ptr, csr_src, dinv, aggb);
    gemm_mfma_kernel<<<ggrid, 256, 0, stream>>>(aggb, W1, b1, flagF, h, 1);

    // ---- layer 2: aggb = A_hat * h ; out = relu(aggb @ W2 + b2) ----
    gather_kernel<<<agrid, 256, 0, stream>>>(h, row_ptr, csr_src, dinv, aggb);
    gemm_mfma_kernel<<<ggrid, 256, 0, stream>>>(aggb, W2, b2, flagF, d_out, 2);
}